// Round 5
// baseline (483.561 us; speedup 1.0000x reference)
//
#include <hip/hip_runtime.h>
#include <hip/hip_bf16.h>

#define N_NODES 8192
#define FIN 512
#define FOUT 64
#define LRELU_ALPHA 0.2f
#define SLAB 512
#define NSLAB (N_NODES / SLAB)   // 16

typedef __attribute__((ext_vector_type(8))) short short8;
typedef __attribute__((ext_vector_type(4))) float floatx4;

static __device__ __forceinline__ short f2bf_bits(float x) {
    union { __hip_bfloat16 b; short s; } u; u.b = __float2bfloat16(x); return u.s;
}

// p = adj>0 ? exp(leakyrelu(ssrc + sdst)) : 0   (a_b folded into ssrc)
static __device__ __forceinline__ float pval(float ssrc, float sd, int adjv) {
    float e = ssrc + sd;
    e = fmaxf(e, LRELU_ALPHA * e);
    float pv = __expf(e);
    return adjv > 0 ? pv : 0.0f;
}

// Kernel A: h = x@W + b; s_src = h@a[:64] + a_b; s_dst = h@a[64:];
// hswz = bf16(h)^T in MFMA-B-fragment-major layout:
//   hswz[((ks*4 + n)*64 + lane)*8 + e] = h[j = ks*32 + (lane>>4)*8 + e][f = n*16 + (lane&15)]
// One wave computes 8 rows (r0 = 8-aligned), so the store is one short8 per lane.
__global__ __launch_bounds__(256) void gat_h(
    const float* __restrict__ x, const float* __restrict__ W,
    const float* __restrict__ bias, const float* __restrict__ a,
    const float* __restrict__ a_b,
    float* __restrict__ s_src, float* __restrict__ s_dst,
    unsigned short* __restrict__ hswz)
{
    const int lane = threadIdx.x & 63;
    const int wave = threadIdx.x >> 6;
    const int r0 = (blockIdx.x * 4 + wave) * 8;   // 8 rows per wave

    float acc[8] = {0.f,0.f,0.f,0.f,0.f,0.f,0.f,0.f};
    const float* x0 = x + (size_t)r0 * FIN;

    #pragma unroll 2
    for (int k = 0; k < FIN; k += 4) {
        float w0 = W[(k + 0) * FOUT + lane];
        float w1 = W[(k + 1) * FOUT + lane];
        float w2 = W[(k + 2) * FOUT + lane];
        float w3 = W[(k + 3) * FOUT + lane];
        #pragma unroll
        for (int rr = 0; rr < 8; ++rr) {
            float4 xv = *reinterpret_cast<const float4*>(x0 + (size_t)rr * FIN + k);
            acc[rr] = fmaf(xv.w, w3, fmaf(xv.z, w2, fmaf(xv.y, w1, fmaf(xv.x, w0, acc[rr]))));
        }
    }
    float bb = bias[lane];
    #pragma unroll
    for (int rr = 0; rr < 8; ++rr) acc[rr] += bb;

    // fragment-major bf16 store: one short8 (16B) per lane covers e=0..7
    {
        const int ks = r0 >> 5;
        const int n = lane >> 4;
        const int lane_dst = (lane & 15) + (((r0 >> 3) & 3) << 4);
        short8 pk;
        #pragma unroll
        for (int rr = 0; rr < 8; ++rr) pk[rr] = f2bf_bits(acc[rr]);
        *reinterpret_cast<short8*>(hswz + (size_t)((ks * 4 + n) * 64 + lane_dst) * 8) = pk;
    }

    float asrc = a[lane], adst = a[FOUT + lane];
    float ab = a_b[0];
    float ss[8], sd[8];
    #pragma unroll
    for (int rr = 0; rr < 8; ++rr) { ss[rr] = acc[rr] * asrc; sd[rr] = acc[rr] * adst; }
    #pragma unroll
    for (int m = 32; m >= 1; m >>= 1) {
        #pragma unroll
        for (int rr = 0; rr < 8; ++rr) {
            ss[rr] += __shfl_xor(ss[rr], m);
            sd[rr] += __shfl_xor(sd[rr], m);
        }
    }
    if (lane == 0) {
        float4 v0 = { ss[0] + ab, ss[1] + ab, ss[2] + ab, ss[3] + ab };
        float4 v1 = { ss[4] + ab, ss[5] + ab, ss[6] + ab, ss[7] + ab };
        float4 u0 = { sd[0], sd[1], sd[2], sd[3] };
        float4 u1 = { sd[4], sd[5], sd[6], sd[7] };
        *reinterpret_cast<float4*>(s_src + r0)     = v0;
        *reinterpret_cast<float4*>(s_src + r0 + 4) = v1;
        *reinterpret_cast<float4*>(s_dst + r0)     = u0;
        *reinterpret_cast<float4*>(s_dst + r0 + 4) = u1;
    }
}

// Kernel B: block = 16 rows x 8 waves. Block-cooperative slab pipeline:
// stage slab s+1 (32 KB, 16 rows x 512 cols, each DMA = 1 KB contiguous of ONE row)
// -> compute slab s (wave w owns cols [w*64, w*64+64)) -> __syncthreads (full drain).
// XOR swizzle (granule ^= row&7) applied to the GLOBAL source; LDS dest linear;
// same XOR on the ds_read address (rule: both-sides-or-neither).
__global__ __launch_bounds__(512) void gat_attn(
    const int* __restrict__ adj,
    const float* __restrict__ s_src,
    const float* __restrict__ s_dst,
    const unsigned short* __restrict__ hswz,
    float* __restrict__ out)
{
    __shared__ __align__(16) char smem[65536];   // 2 x 32KB slab buffers; epilogue overlays

    const int lane = threadIdx.x & 63;
    const int wave = threadIdx.x >> 6;
    const int i0 = blockIdx.x * 16;
    const int r = lane & 15;
    const int ko = (lane >> 4) * 8;

    const float ssrc = s_src[i0 + r];
    floatx4 acc[4] = { {0.f,0.f,0.f,0.f},{0.f,0.f,0.f,0.f},
                       {0.f,0.f,0.f,0.f},{0.f,0.f,0.f,0.f} };
    float denom = 0.f;

    char* buf0 = smem;
    char* buf1 = smem + 32768;

    // stage slab s: wave w DMAs rows 2w, 2w+1 (2 halves each = 4 x 1KB)
    auto stage = [&](char* buf, int s) {
        #pragma unroll
        for (int q = 0; q < 4; ++q) {
            const int row = wave * 2 + (q >> 1);
            const int half = q & 1;
            const int* g = adj + (size_t)(i0 + row) * N_NODES + s * SLAB
                         + half * 256 + ((lane ^ (row & 7)) << 2);
            __builtin_amdgcn_global_load_lds(
                (const __attribute__((address_space(1))) int*)g,
                (__attribute__((address_space(3))) int*)(buf + row * 2048 + half * 1024),
                16, 0, 0);
        }
    };

    stage(buf0, 0);
    __syncthreads();

    for (int s = 0; s < NSLAB; ++s) {
        const char* cur = (s & 1) ? buf1 : buf0;
        char* nxt = (s & 1) ? buf0 : buf1;
        if (s + 1 < NSLAB) stage(nxt, s + 1);

        const int rbase = r * 2048;
        #pragma unroll
        for (int kk = 0; kk < 2; ++kk) {
            const int c0 = wave * 64 + kk * 32 + ko;          // col in slab, 0..511
            const int hb = (c0 >> 8) << 10;                   // half base (bytes)
            const int c = c0 & 255;                           // col within half
            const int g0 = (((c >> 2) + 0) ^ (r & 7)) << 4;   // 16B granule, swizzled
            const int g1 = (((c >> 2) + 1) ^ (r & 7)) << 4;
            int4 A0 = *reinterpret_cast<const int4*>(cur + rbase + hb + g0);
            int4 A1 = *reinterpret_cast<const int4*>(cur + rbase + hb + g1);
            const int jb = s * SLAB + c0;
            float4 S0 = *reinterpret_cast<const float4*>(s_dst + jb);
            float4 S1 = *reinterpret_cast<const float4*>(s_dst + jb + 4);
            float p0 = pval(ssrc, S0.x, A0.x);
            float p1 = pval(ssrc, S0.y, A0.y);
            float p2 = pval(ssrc, S0.z, A0.z);
            float p3 = pval(ssrc, S0.w, A0.w);
            float p4 = pval(ssrc, S1.x, A1.x);
            float p5 = pval(ssrc, S1.y, A1.y);
            float p6 = pval(ssrc, S1.z, A1.z);
            float p7 = pval(ssrc, S1.w, A1.w);
            denom += ((p0 + p1) + (p2 + p3)) + ((p4 + p5) + (p6 + p7));
            short8 af;
            af[0] = f2bf_bits(p0); af[1] = f2bf_bits(p1);
            af[2] = f2bf_bits(p2); af[3] = f2bf_bits(p3);
            af[4] = f2bf_bits(p4); af[5] = f2bf_bits(p5);
            af[6] = f2bf_bits(p6); af[7] = f2bf_bits(p7);
            const int ks = (jb >> 5);                          // = s*16 + wave*2 + kk
            #pragma unroll
            for (int n = 0; n < 4; ++n) {
                short8 bf = *reinterpret_cast<const short8*>(
                    hswz + (size_t)((ks * 4 + n) * 64 + lane) * 8);
                acc[n] = __builtin_amdgcn_mfma_f32_16x16x32_bf16(af, bf, acc[n], 0, 0, 0);
            }
        }
        __syncthreads();   // drains this wave's stage DMAs + barriers buffer swap
    }

    // reduce denom over the 4 ko-groups (lanes sharing lane&15)
    denom += __shfl_xor(denom, 16);
    denom += __shfl_xor(denom, 32);

    // loop's trailing __syncthreads guarantees all waves are done with LDS tiles
    floatx4* redbuf = (floatx4*)smem;          // [8][4][64] = 32 KB
    float* dred = (float*)(smem + 32768);      // [8][16]
    #pragma unroll
    for (int n = 0; n < 4; ++n) redbuf[(wave * 4 + n) * 64 + lane] = acc[n];
    if (lane < 16) dred[wave * 16 + lane] = denom;
    __syncthreads();

    if (wave < 4) {
        floatx4 facc = redbuf[wave * 64 + lane];
        #pragma unroll
        for (int v = 1; v < 8; ++v) facc += redbuf[(v * 4 + wave) * 64 + lane];
        #pragma unroll
        for (int e = 0; e < 4; ++e) {
            const int r2 = (lane >> 4) * 4 + e;
            float dn = 0.f;
            #pragma unroll
            for (int v = 0; v < 8; ++v) dn += dred[v * 16 + r2];
            float val = facc[e] / dn;
            val = val > 0.f ? val : (__expf(val) - 1.f);   // ELU
            out[(size_t)(i0 + r2) * FOUT + wave * 16 + (lane & 15)] = val;
        }
    }
}

extern "C" void kernel_launch(void* const* d_in, const int* in_sizes, int n_in,
                              void* d_out, int out_size, void* d_ws, size_t ws_size,
                              hipStream_t stream) {
    const float* x   = (const float*)d_in[0];
    const int*   adj = (const int*)d_in[1];
    const float* W   = (const float*)d_in[2];
    const float* b   = (const float*)d_in[3];
    const float* a   = (const float*)d_in[4];
    const float* a_b = (const float*)d_in[5];
    float* out = (float*)d_out;

    char* ws = (char*)d_ws;
    float* s_src = (float*)ws;                                 // 32 KB
    float* s_dst = (float*)(ws + 32 * 1024);                   // 32 KB
    unsigned short* hswz = (unsigned short*)(ws + 64 * 1024);  // 1 MB

    hipLaunchKernelGGL(gat_h, dim3(N_NODES / 32), dim3(256), 0, stream,
                       x, W, b, a, a_b, s_src, s_dst, hswz);
    // MEASUREMENT ROUND: gat_attn is idempotent (reads adj/s_src/s_dst/hswz,
    // writes out deterministically). Launch 5x: dur = A + 5B; with r4's
    // A + B = 136 us this solves the gat_h/gat_attn split: B = (dur-136)/4.
    for (int rep = 0; rep < 5; ++rep) {
        hipLaunchKernelGGL(gat_attn, dim3(N_NODES / 16), dim3(512), 0, stream,
                           adj, s_src, s_dst, hswz, out);
    }
}

// Round 6
// 164.205 us; speedup vs baseline: 2.9449x; 2.9449x over previous
//
#include <hip/hip_runtime.h>
#include <hip/hip_bf16.h>

#define N_NODES 8192
#define FIN 512
#define FOUT 64
#define LRELU_ALPHA 0.2f

typedef __attribute__((ext_vector_type(8))) short short8;
typedef __attribute__((ext_vector_type(4))) float floatx4;

static __device__ __forceinline__ short f2bf_bits(float x) {
    union { __hip_bfloat16 b; short s; } u; u.b = __float2bfloat16(x); return u.s;
}

// ---------------------------------------------------------------------------
// Kernel 0: adj (int32 0/1, 256 MB) -> bitmask (8 MB). Pure streaming.
// Wave wid handles row wid (8192 rows, 128 x 64-bit masks per row, contiguous).
__global__ __launch_bounds__(256) void adj_bits(
    const int* __restrict__ adj, unsigned long long* __restrict__ bits)
{
    const int lane = threadIdx.x & 63;
    const int wid = blockIdx.x * 4 + (threadIdx.x >> 6);   // 0..8191 = row
    const size_t base = (size_t)wid * 128;                 // mask index
    const int* src = adj + base * 64 + lane;
    #pragma unroll 8
    for (int t = 0; t < 128; ++t) {
        int v = src[t * 64];
        unsigned long long m = __ballot(v > 0);
        if (lane == 0) bits[base + t] = m;
    }
}

// ---------------------------------------------------------------------------
// Kernel A: h = x@W + b; s_src = h@a[:64] + a_b; s_dst = h@a[64:];
// hswz = bf16(h)^T fragment-major (same layout as prior rounds).
// Block = 16 rows x 4 waves; wave w owns rows 4w..4w+3 (private!).
// x staged via global_load_lds, double-buffered, drain-at-top (no barriers).
#define GH_KT 128
__global__ __launch_bounds__(256) void gat_h(
    const float* __restrict__ x, const float* __restrict__ W,
    const float* __restrict__ bias, const float* __restrict__ a,
    const float* __restrict__ a_b,
    float* __restrict__ s_src, float* __restrict__ s_dst,
    unsigned short* __restrict__ hswz)
{
    __shared__ __align__(16) float xlds[2][16][GH_KT];   // 2 x 8 KB

    const int lane = threadIdx.x & 63;
    const int wave = threadIdx.x >> 6;
    const int i0 = blockIdx.x * 16;
    const int r0 = i0 + wave * 4;      // this wave's 4 rows (4-aligned)

    // stage tile kt into buf: wave w fills xlds[buf][4w..4w+3][:] (2 DMAs x 1KB)
    auto stage = [&](int buf, int k0) {
        #pragma unroll
        for (int d = 0; d < 2; ++d) {
            const int row = wave * 4 + d * 2 + (lane >> 5);
            const float* g = x + (size_t)(i0 + row) * FIN + k0 + (lane & 31) * 4;
            __builtin_amdgcn_global_load_lds(
                (const __attribute__((address_space(1))) float*)g,
                (__attribute__((address_space(3))) float*)&xlds[buf][wave * 4 + d * 2][0],
                16, 0, 0);
        }
    };

    float acc0 = 0.f, acc1 = 0.f, acc2 = 0.f, acc3 = 0.f;

    stage(0, 0);
    for (int kt = 0; kt < FIN / GH_KT; ++kt) {
        // drain: own stage(kt) DMAs have landed (issued one full tile ago or just above)
        asm volatile("s_waitcnt vmcnt(0)" ::: "memory");
        __builtin_amdgcn_sched_barrier(0);
        if (kt + 1 < FIN / GH_KT) stage((kt + 1) & 1, (kt + 1) * GH_KT);

        const float* xt = &xlds[kt & 1][wave * 4][0];
        const int k0 = kt * GH_KT;
        #pragma unroll 4
        for (int k4 = 0; k4 < GH_KT / 4; ++k4) {
            float w0 = W[(k0 + k4 * 4 + 0) * FOUT + lane];
            float w1 = W[(k0 + k4 * 4 + 1) * FOUT + lane];
            float w2 = W[(k0 + k4 * 4 + 2) * FOUT + lane];
            float w3 = W[(k0 + k4 * 4 + 3) * FOUT + lane];
            float4 xa = *reinterpret_cast<const float4*>(xt + 0 * GH_KT + k4 * 4);
            float4 xb = *reinterpret_cast<const float4*>(xt + 1 * GH_KT + k4 * 4);
            float4 xc = *reinterpret_cast<const float4*>(xt + 2 * GH_KT + k4 * 4);
            float4 xd = *reinterpret_cast<const float4*>(xt + 3 * GH_KT + k4 * 4);
            acc0 = fmaf(xa.w, w3, fmaf(xa.z, w2, fmaf(xa.y, w1, fmaf(xa.x, w0, acc0))));
            acc1 = fmaf(xb.w, w3, fmaf(xb.z, w2, fmaf(xb.y, w1, fmaf(xb.x, w0, acc1))));
            acc2 = fmaf(xc.w, w3, fmaf(xc.z, w2, fmaf(xc.y, w1, fmaf(xc.x, w0, acc2))));
            acc3 = fmaf(xd.w, w3, fmaf(xd.z, w2, fmaf(xd.y, w1, fmaf(xd.x, w0, acc3))));
        }
    }

    float bb = bias[lane];
    acc0 += bb; acc1 += bb; acc2 += bb; acc3 += bb;

    // fragment-major bf16 store (4 rows -> ushort4 at e0 = r0&7)
    {
        const int ks = r0 >> 5;
        const int n = lane >> 4;
        const int lane_dst = (lane & 15) + (((r0 >> 3) & 3) << 4);
        const int e0 = r0 & 7;
        ushort4 pk;
        pk.x = (unsigned short)f2bf_bits(acc0);
        pk.y = (unsigned short)f2bf_bits(acc1);
        pk.z = (unsigned short)f2bf_bits(acc2);
        pk.w = (unsigned short)f2bf_bits(acc3);
        *reinterpret_cast<ushort4*>(
            hswz + (size_t)((ks * 4 + n) * 64 + lane_dst) * 8 + e0) = pk;
    }

    float asrc = a[lane], adst = a[FOUT + lane];
    float ab = a_b[0];
    float ss0 = acc0 * asrc, ss1 = acc1 * asrc, ss2 = acc2 * asrc, ss3 = acc3 * asrc;
    float sd0 = acc0 * adst, sd1 = acc1 * adst, sd2 = acc2 * adst, sd3 = acc3 * adst;
    #pragma unroll
    for (int m = 32; m >= 1; m >>= 1) {
        ss0 += __shfl_xor(ss0, m); ss1 += __shfl_xor(ss1, m);
        ss2 += __shfl_xor(ss2, m); ss3 += __shfl_xor(ss3, m);
        sd0 += __shfl_xor(sd0, m); sd1 += __shfl_xor(sd1, m);
        sd2 += __shfl_xor(sd2, m); sd3 += __shfl_xor(sd3, m);
    }
    if (lane == 0) {
        float4 vs = { ss0 + ab, ss1 + ab, ss2 + ab, ss3 + ab };
        float4 vd = { sd0, sd1, sd2, sd3 };
        *reinterpret_cast<float4*>(s_src + r0) = vs;
        *reinterpret_cast<float4*>(s_dst + r0) = vd;
    }
}

// ---------------------------------------------------------------------------
// Kernel B: block = 16 rows x 8 waves. adj-bits tile (16 KB) staged once into
// padded LDS (row stride 1040 B: 2-way-max bank aliasing = free). Main loop:
// NO global adj traffic, NO barriers, NO DMA — bits from LDS, s_dst from L1,
// hswz B-frags from L2, pval VALU, MFMA accumulate.
__global__ __launch_bounds__(512) void gat_attn(
    const unsigned int* __restrict__ bits,   // [8192][256] dwords
    const float* __restrict__ s_src,
    const float* __restrict__ s_dst,
    const unsigned short* __restrict__ hswz,
    float* __restrict__ out)
{
    __shared__ __align__(16) char smem[33280];  // bits: 16*1040=16640; epilogue overlay 33280

    const int lane = threadIdx.x & 63;
    const int wave = threadIdx.x >> 6;
    const int i0 = blockIdx.x * 16;
    const int r = lane & 15;
    const int g = lane >> 4;              // 0..3 (ko = g*8)

    // stage bits tile: 1024 uint4 / 512 threads = 2 each, coalesced
    #pragma unroll
    for (int i = 0; i < 2; ++i) {
        const int c = threadIdx.x + i * 512;      // uint4 index
        const int row = c >> 6, col = c & 63;
        uint4 v = *reinterpret_cast<const uint4*>(bits + (size_t)(i0 + row) * 256 + col * 4);
        *reinterpret_cast<uint4*>(smem + row * 1040 + col * 16) = v;
    }
    __syncthreads();

    const float ssrc = s_src[i0 + r];
    floatx4 acc[4] = { {0.f,0.f,0.f,0.f},{0.f,0.f,0.f,0.f},
                       {0.f,0.f,0.f,0.f},{0.f,0.f,0.f,0.f} };
    float denom = 0.f;

    const char* bl = smem + r * 1040 + (wave << 3);

    for (int s = 0; s < 16; ++s) {
        uint2 bw = *reinterpret_cast<const uint2*>(bl + s * 64);
        #pragma unroll
        for (int kk = 0; kk < 2; ++kk) {
            const unsigned byte = ((kk ? bw.y : bw.x) >> (g * 8)) & 0xffu;
            const int jb = s * 512 + wave * 64 + kk * 32 + g * 8;
            float4 S0 = *reinterpret_cast<const float4*>(s_dst + jb);
            float4 S1 = *reinterpret_cast<const float4*>(s_dst + jb + 4);
            float e0 = ssrc + S0.x, e1 = ssrc + S0.y, e2 = ssrc + S0.z, e3 = ssrc + S0.w;
            float e4 = ssrc + S1.x, e5 = ssrc + S1.y, e6 = ssrc + S1.z, e7 = ssrc + S1.w;
            e0 = fmaxf(e0, LRELU_ALPHA * e0); e1 = fmaxf(e1, LRELU_ALPHA * e1);
            e2 = fmaxf(e2, LRELU_ALPHA * e2); e3 = fmaxf(e3, LRELU_ALPHA * e3);
            e4 = fmaxf(e4, LRELU_ALPHA * e4); e5 = fmaxf(e5, LRELU_ALPHA * e5);
            e6 = fmaxf(e6, LRELU_ALPHA * e6); e7 = fmaxf(e7, LRELU_ALPHA * e7);
            float p0 = (byte & 1u)   ? __expf(e0) : 0.f;
            float p1 = (byte & 2u)   ? __expf(e1) : 0.f;
            float p2 = (byte & 4u)   ? __expf(e2) : 0.f;
            float p3 = (byte & 8u)   ? __expf(e3) : 0.f;
            float p4 = (byte & 16u)  ? __expf(e4) : 0.f;
            float p5 = (byte & 32u)  ? __expf(e5) : 0.f;
            float p6 = (byte & 64u)  ? __expf(e6) : 0.f;
            float p7 = (byte & 128u) ? __expf(e7) : 0.f;
            denom += ((p0 + p1) + (p2 + p3)) + ((p4 + p5) + (p6 + p7));
            short8 af;
            af[0] = f2bf_bits(p0); af[1] = f2bf_bits(p1);
            af[2] = f2bf_bits(p2); af[3] = f2bf_bits(p3);
            af[4] = f2bf_bits(p4); af[5] = f2bf_bits(p5);
            af[6] = f2bf_bits(p6); af[7] = f2bf_bits(p7);
            const int ks = s * 16 + wave * 2 + kk;
            #pragma unroll
            for (int n = 0; n < 4; ++n) {
                short8 bf = *reinterpret_cast<const short8*>(
                    hswz + (size_t)((ks * 4 + n) * 64 + lane) * 8);
                acc[n] = __builtin_amdgcn_mfma_f32_16x16x32_bf16(af, bf, acc[n], 0, 0, 0);
            }
        }
    }

    // reduce denom over the 4 g-groups (lanes sharing lane&15)
    denom += __shfl_xor(denom, 16);
    denom += __shfl_xor(denom, 32);

    __syncthreads();   // all waves done with bits LDS; reuse for reduction
    floatx4* redbuf = (floatx4*)smem;          // [8][4][64] = 32 KB
    float* dred = (float*)(smem + 32768);      // [8][16]
    #pragma unroll
    for (int n = 0; n < 4; ++n) redbuf[(wave * 4 + n) * 64 + lane] = acc[n];
    if (lane < 16) dred[wave * 16 + lane] = denom;
    __syncthreads();

    if (wave < 4) {
        floatx4 facc = redbuf[wave * 64 + lane];
        #pragma unroll
        for (int v = 1; v < 8; ++v) facc += redbuf[(v * 4 + wave) * 64 + lane];
        #pragma unroll
        for (int e = 0; e < 4; ++e) {
            const int r2 = (lane >> 4) * 4 + e;
            float dn = 0.f;
            #pragma unroll
            for (int v = 0; v < 8; ++v) dn += dred[v * 16 + r2];
            float val = facc[e] / dn;
            val = val > 0.f ? val : (__expf(val) - 1.f);   // ELU
            out[(size_t)(i0 + r2) * FOUT + wave * 16 + (lane & 15)] = val;
        }
    }
}

extern "C" void kernel_launch(void* const* d_in, const int* in_sizes, int n_in,
                              void* d_out, int out_size, void* d_ws, size_t ws_size,
                              hipStream_t stream) {
    const float* x   = (const float*)d_in[0];
    const int*   adj = (const int*)d_in[1];
    const float* W   = (const float*)d_in[2];
    const float* b   = (const float*)d_in[3];
    const float* a   = (const float*)d_in[4];
    const float* a_b = (const float*)d_in[5];
    float* out = (float*)d_out;

    char* ws = (char*)d_ws;
    float* s_src = (float*)ws;                                      // 32 KB
    float* s_dst = (float*)(ws + 32 * 1024);                        // 32 KB
    unsigned short* hswz = (unsigned short*)(ws + 64 * 1024);       // 1 MB
    unsigned long long* bitsW = (unsigned long long*)(ws + 64 * 1024 + 1024 * 1024); // 8 MB
    const unsigned int* bitsR = (const unsigned int*)bitsW;

    hipLaunchKernelGGL(adj_bits, dim3(N_NODES / 4), dim3(256), 0, stream, adj, bitsW);
    hipLaunchKernelGGL(gat_h, dim3(N_NODES / 16), dim3(256), 0, stream,
                       x, W, b, a, a_b, s_src, s_dst, hswz);
    hipLaunchKernelGGL(gat_attn, dim3(N_NODES / 16), dim3(512), 0, stream,
                       bitsR, s_src, s_dst, hswz, out);
}